// Round 15
// baseline (342.649 us; speedup 1.0000x reference)
//
#include <hip/hip_runtime.h>
#include <hip/hip_bf16.h>
#include <math.h>

#define NN 50000
#define EE 800000
#define INCH 512
#define C1 256     // H1*HID
#define NC 16
#define NEG 0.2f
#define BSTRIDE 64   // bucket slots/node; Poisson(16): P(deg>=64)~1e-18/node, max over 50K ~40

typedef __attribute__((ext_vector_type(8))) short bf16x8;
typedef __attribute__((ext_vector_type(4))) float f32x4;

__device__ inline short f2bf(float f) {
    __hip_bfloat16 h = __float2bfloat16(f);
    return *reinterpret_cast<short*>(&h);
}

__device__ inline void unpack4(uint2 rv, float& v0, float& v1, float& v2, float& v3) {
    v0 = __uint_as_float(rv.x << 16);
    v1 = __uint_as_float(rv.x & 0xFFFF0000u);
    v2 = __uint_as_float(rv.y << 16);
    v3 = __uint_as_float(rv.y & 0xFFFF0000u);
}

// -------- W1 transpose + bf16 (W2 transpose in block (0,0); cnt zeroing spread over grid) --------
__global__ __launch_bounds__(256) void k_w1t(const float* __restrict__ W1,
                                             __hip_bfloat16* __restrict__ W1t,
                                             const float* __restrict__ W2,
                                             __hip_bfloat16* __restrict__ w2t,
                                             int* __restrict__ cnt) {
    int blin = blockIdx.y * gridDim.x + blockIdx.x;   // 0..127
    for (int i = blin * 256 + threadIdx.x; i < NN; i += 128 * 256) cnt[i] = 0;
    if (blin == 0) {
        int t = threadIdx.x;
#pragma unroll
        for (int c = 0; c < NC; c++)
            w2t[(size_t)c * C1 + t] = __float2bfloat16(W2[(size_t)t * NC + c]);
    }
    __shared__ float t[32][33];
    int k0 = blockIdx.x * 32, n0 = blockIdx.y * 32;
    int tx = threadIdx.x & 31, ty = threadIdx.x >> 5;  // ty 0..7
#pragma unroll
    for (int i = 0; i < 4; i++) {
        t[ty + i * 8][tx] = W1[(size_t)(k0 + ty + i * 8) * C1 + n0 + tx];
    }
    __syncthreads();
#pragma unroll
    for (int i = 0; i < 4; i++) {
        W1t[(size_t)(n0 + ty + i * 8) * INCH + k0 + tx] = __float2bfloat16(t[tx][ty + i * 8]);
    }
}

// ---------------- GEMM1 (bf16 MFMA, 64x64 tile) + chunk-interleaved bucket CSR build ------
// Block map: chunk c = l>>3 (8 blocks). c<782: even c -> gemm chunk c/2, odd c -> edge chunk
// c/2 (gemm & edge co-resident; XCD key l&7 == idx&7 preserved). c==782: gemm chunk 391.
#define BM3 64
#define BK3 64
#define NBM 782            // ceil(NN/64)
#define TOTAL_BLKS (783 * 8)
__global__ __launch_bounds__(256) void k_gemm1(const float* __restrict__ x,
                                               const __hip_bfloat16* __restrict__ W1t,
                                               const float* __restrict__ as1,
                                               const float* __restrict__ ad1,
                                               unsigned short* __restrict__ h1b,
                                               float* __restrict__ a_src,
                                               float* __restrict__ a_dst,
                                               const int* __restrict__ esrc,
                                               const int* __restrict__ edst,
                                               int* __restrict__ cnt,
                                               int* __restrict__ bucket) {
    int l = blockIdx.x;
    int c = l >> 3, w8 = l & 7;
    int idx; bool is_edge;
    if (c < 782) { is_edge = (c & 1); idx = (c >> 1) * 8 + w8; }
    else         { is_edge = false;   idx = 391 * 8 + w8; }
    if (is_edge) {
        int e = idx * 256 + threadIdx.x;
        if (e < EE) {
            int d = edst[e];
            int s = esrc[e];
            int pos = atomicAdd(&cnt[d], 1);
            if (pos < BSTRIDE) bucket[(size_t)d * BSTRIDE + pos] = s;
        }
        return;
    }
    int g = idx >> 5, r = idx & 31;
    int head = r >> 3, slot = r & 7;
    int bmi = g * 8 + slot;
    if (bmi >= NBM) return;
    int bm = bmi * BM3;
    int bn = head * 64;

    __shared__ __align__(16) short Ah[BM3 * BK3];   // 8 KB
    __shared__ __align__(16) short Bl[BM3 * BK3];   // 8 KB
    int tid = threadIdx.x;
    int wm = tid >> 6, lane = tid & 63;
    int quad = lane >> 4, l16 = lane & 15;

    f32x4 acc[4];
#pragma unroll
    for (int j = 0; j < 4; j++) acc[j] = (f32x4){0.f, 0.f, 0.f, 0.f};

    for (int kt = 0; kt < INCH; kt += BK3) {
#pragma unroll
        for (int i = 0; i < 4; i++) {
            int idx2 = tid + 256 * i;
            int row = idx2 >> 4, c4 = idx2 & 15;
            int m = bm + row; if (m >= NN) m = NN - 1;
            float4 v = *(const float4*)&x[(size_t)m * INCH + kt + c4 * 4];
            short4 h4 = make_short4(f2bf(v.x), f2bf(v.y), f2bf(v.z), f2bf(v.w));
            int swc = (c4 >> 1) ^ (row & 7);
            *(short4*)&Ah[row * BK3 + swc * 8 + (c4 & 1) * 4] = h4;
        }
#pragma unroll
        for (int i = 0; i < 2; i++) {
            int idx2 = tid + 256 * i;
            int row = idx2 >> 3, c8 = idx2 & 7;
            float4 v = *(const float4*)(W1t + (size_t)(bn + row) * INCH + kt + c8 * 8);
            int swc = c8 ^ (row & 7);
            *(float4*)&Bl[row * BK3 + swc * 8] = v;
        }
        __syncthreads();
#pragma unroll
        for (int ks = 0; ks < 2; ks++) {
            int lc = (ks * 4 + quad);
            bf16x8 af, bfr[4];
            {
                int row = wm * 16 + l16;
                af = *(bf16x8*)&Ah[row * BK3 + (lc ^ (l16 & 7)) * 8];
            }
#pragma unroll
            for (int ni = 0; ni < 4; ni++) {
                int row = ni * 16 + l16;
                bfr[ni] = *(bf16x8*)&Bl[row * BK3 + (lc ^ (l16 & 7)) * 8];
            }
#pragma unroll
            for (int ni = 0; ni < 4; ni++)
                acc[ni] = __builtin_amdgcn_mfma_f32_16x16x32_bf16(af, bfr[ni], acc[ni], 0, 0, 0);
        }
        __syncthreads();
    }
    // store h1 as bf16 (C/D layout: col=l16, row=quad*4+r)
#pragma unroll
    for (int r2 = 0; r2 < 4; r2++) {
        int gm = bm + wm * 16 + quad * 4 + r2;
        if (gm < NN) {
#pragma unroll
            for (int ni = 0; ni < 4; ni++)
                h1b[(size_t)gm * C1 + bn + ni * 16 + l16] = (unsigned short)f2bf(acc[ni][r2]);
        }
    }
    // fused attention logits: wave covers the full head (64 cols)
    float aw[4], dw[4];
#pragma unroll
    for (int ni = 0; ni < 4; ni++) {
        aw[ni] = as1[bn + ni * 16 + l16];
        dw[ni] = ad1[bn + ni * 16 + l16];
    }
#pragma unroll
    for (int r2 = 0; r2 < 4; r2++) {
        float ps = acc[0][r2] * aw[0] + acc[1][r2] * aw[1] + acc[2][r2] * aw[2] + acc[3][r2] * aw[3];
        float pd = acc[0][r2] * dw[0] + acc[1][r2] * dw[1] + acc[2][r2] * dw[2] + acc[3][r2] * dw[3];
#pragma unroll
        for (int off = 8; off; off >>= 1) {
            ps += __shfl_xor(ps, off, 16);
            pd += __shfl_xor(pd, off, 16);
        }
        if (l16 == 0) {
            int gm = bm + wm * 16 + quad * 4 + r2;
            if (gm < NN) {
                a_src[gm * 4 + head] = ps;
                a_dst[gm * 4 + head] = pd;
            }
        }
    }
}

// ---------------- layer-1 aggregation: one wave per node, 4 ch/lane -> bf16 h2in ----------
__global__ __launch_bounds__(256) void k_agg1(const unsigned short* __restrict__ h1b,
                                              const int* __restrict__ bucket,
                                              const int* __restrict__ cnt,
                                              const float* __restrict__ a_src, const float* __restrict__ a_dst,
                                              const float* __restrict__ b1,
                                              unsigned short* __restrict__ h2inb) {
    int tid = threadIdx.x;
    int wv = tid >> 6, lane = tid & 63;
    int n = blockIdx.x * 4 + wv;
    if (n >= NN) return;
    int head = lane >> 4;
    const uint2* rows = (const uint2*)h1b;

    float adn = a_dst[n * 4 + head];
    float es = a_src[n * 4 + head] + adn;
    es = fmaxf(es, NEG * es);
    float wse = __expf(es);
    float denom = wse;
    float a0, a1, a2, a3;
    {
        uint2 rv = rows[(size_t)n * 64 + lane];
        float v0, v1, v2, v3;
        unpack4(rv, v0, v1, v2, v3);
        a0 = wse * v0; a1 = wse * v1; a2 = wse * v2; a3 = wse * v3;
    }

    size_t base = (size_t)n * BSTRIDE;
    int deg = cnt[n]; if (deg > BSTRIDE) deg = BSTRIDE;
    int sv = 0;
    if (lane < deg) sv = bucket[base + lane];
    int k = 0;
    for (; k + 4 <= deg; k += 4) {
        int s0 = __shfl(sv, k + 0), s1 = __shfl(sv, k + 1);
        int s2 = __shfl(sv, k + 2), s3 = __shfl(sv, k + 3);
        float e0 = a_src[s0 * 4 + head] + adn;
        float e1 = a_src[s1 * 4 + head] + adn;
        float e2 = a_src[s2 * 4 + head] + adn;
        float e3 = a_src[s3 * 4 + head] + adn;
        uint2 r0 = rows[(size_t)s0 * 64 + lane];
        uint2 r1 = rows[(size_t)s1 * 64 + lane];
        uint2 r2 = rows[(size_t)s2 * 64 + lane];
        uint2 r3 = rows[(size_t)s3 * 64 + lane];
        e0 = fmaxf(e0, NEG * e0); e1 = fmaxf(e1, NEG * e1);
        e2 = fmaxf(e2, NEG * e2); e3 = fmaxf(e3, NEG * e3);
        float w0 = __expf(e0), w1 = __expf(e1), w2 = __expf(e2), w3 = __expf(e3);
        float v0, v1, v2, v3;
        unpack4(r0, v0, v1, v2, v3);
        denom += w0; a0 += w0 * v0; a1 += w0 * v1; a2 += w0 * v2; a3 += w0 * v3;
        unpack4(r1, v0, v1, v2, v3);
        denom += w1; a0 += w1 * v0; a1 += w1 * v1; a2 += w1 * v2; a3 += w1 * v3;
        unpack4(r2, v0, v1, v2, v3);
        denom += w2; a0 += w2 * v0; a1 += w2 * v1; a2 += w2 * v2; a3 += w2 * v3;
        unpack4(r3, v0, v1, v2, v3);
        denom += w3; a0 += w3 * v0; a1 += w3 * v1; a2 += w3 * v2; a3 += w3 * v3;
    }
    for (; k < deg; k++) {
        int s0 = __shfl(sv, k);
        float e0 = a_src[s0 * 4 + head] + adn;
        uint2 r0 = rows[(size_t)s0 * 64 + lane];
        e0 = fmaxf(e0, NEG * e0);
        float w0 = __expf(e0);
        float v0, v1, v2, v3;
        unpack4(r0, v0, v1, v2, v3);
        denom += w0; a0 += w0 * v0; a1 += w0 * v1; a2 += w0 * v2; a3 += w0 * v3;
    }
    float inv = 1.f / denom;
    float4 bv = *(const float4*)&b1[lane * 4];
    float o0 = a0 * inv + bv.x, o1 = a1 * inv + bv.y;
    float o2 = a2 * inv + bv.z, o3 = a3 * inv + bv.w;
    o0 = o0 > 0.f ? o0 : expm1f(o0);
    o1 = o1 > 0.f ? o1 : expm1f(o1);
    o2 = o2 > 0.f ? o2 : expm1f(o2);
    o3 = o3 > 0.f ? o3 : expm1f(o3);
    uint2 pk;
    pk.x = (unsigned int)(unsigned short)f2bf(o0) | ((unsigned int)(unsigned short)f2bf(o1) << 16);
    pk.y = (unsigned int)(unsigned short)f2bf(o2) | ((unsigned int)(unsigned short)f2bf(o3) << 16);
    *(uint2*)&h2inb[(size_t)n * C1 + lane * 4] = pk;
}

// ---------------- GEMM2 via MFMA: h2[NN,16] = h2in(bf16) @ W2, fused layer-2 logits -------
__global__ __launch_bounds__(256) void k_gemm2(const unsigned short* __restrict__ h2inb,
                                               const __hip_bfloat16* __restrict__ w2t,
                                               const float* __restrict__ as2, const float* __restrict__ ad2,
                                               float* __restrict__ h2,
                                               float* __restrict__ a_src2, float* __restrict__ a_dst2) {
    int tid = threadIdx.x;
    int wave = tid >> 6, lane = tid & 63;
    int quad = lane >> 4, l16 = lane & 15;
    int mbase = blockIdx.x * 64 + wave * 16;
    if (mbase >= NN) return;
    int mrow = mbase + l16; if (mrow >= NN) mrow = NN - 1;
    const bf16x8* arow = (const bf16x8*)(h2inb + (size_t)mrow * C1);
    f32x4 acc = (f32x4){0.f, 0.f, 0.f, 0.f};
#pragma unroll
    for (int ks = 0; ks < 8; ks++) {
        bf16x8 af = arow[ks * 4 + quad];
        bf16x8 bfv = *(const bf16x8*)(w2t + (size_t)l16 * C1 + ks * 32 + quad * 8);
        acc = __builtin_amdgcn_mfma_f32_16x16x32_bf16(af, bfv, acc, 0, 0, 0);
    }
    float a2 = as2[l16], d2 = ad2[l16];
#pragma unroll
    for (int r = 0; r < 4; r++) {
        int gm = mbase + quad * 4 + r;
        if (gm < NN) h2[(size_t)gm * NC + l16] = acc[r];
        float pa = acc[r] * a2, pb = acc[r] * d2;
#pragma unroll
        for (int off = 8; off; off >>= 1) {
            pa += __shfl_xor(pa, off, 16);
            pb += __shfl_xor(pb, off, 16);
        }
        if (l16 == 0 && gm < NN) {
            a_src2[gm] = pa;
            a_dst2[gm] = pb;
        }
    }
}

// ---------------- layer-2 aggregation: fused softmax + gather + bias -> out ----------------
__global__ __launch_bounds__(256) void k_agg2(const float* __restrict__ h2,
                                              const int* __restrict__ bucket,
                                              const int* __restrict__ cnt,
                                              const float* __restrict__ a_src2, const float* __restrict__ a_dst2,
                                              const float* __restrict__ b2, float* __restrict__ out) {
    int tid = threadIdx.x;
    int r = tid >> 4, col = tid & 15;
    int n = blockIdx.x * 16 + r;
    if (n >= NN) return;
    float adn = a_dst2[n];
    float es = a_src2[n] + adn;
    es = fmaxf(es, NEG * es);
    float wse = __expf(es);
    float denom = wse;
    float acc = wse * h2[(size_t)n * NC + col];
    size_t base = (size_t)n * BSTRIDE;
    int deg = cnt[n]; if (deg > BSTRIDE) deg = BSTRIDE;
    int k = 0;
    for (; k + 4 <= deg; k += 4) {
        int s0 = bucket[base + k + 0], s1 = bucket[base + k + 1];
        int s2 = bucket[base + k + 2], s3 = bucket[base + k + 3];
        float e0 = a_src2[s0] + adn, e1 = a_src2[s1] + adn;
        float e2 = a_src2[s2] + adn, e3 = a_src2[s3] + adn;
        float v0 = h2[(size_t)s0 * NC + col], v1 = h2[(size_t)s1 * NC + col];
        float v2 = h2[(size_t)s2 * NC + col], v3 = h2[(size_t)s3 * NC + col];
        e0 = fmaxf(e0, NEG * e0); e1 = fmaxf(e1, NEG * e1);
        e2 = fmaxf(e2, NEG * e2); e3 = fmaxf(e3, NEG * e3);
        float w0 = __expf(e0), w1 = __expf(e1), w2 = __expf(e2), w3 = __expf(e3);
        denom += w0; acc += w0 * v0;
        denom += w1; acc += w1 * v1;
        denom += w2; acc += w2 * v2;
        denom += w3; acc += w3 * v3;
    }
    for (; k < deg; k++) {
        int s0 = bucket[base + k];
        float e0 = a_src2[s0] + adn;
        e0 = fmaxf(e0, NEG * e0);
        float w0 = __expf(e0);
        denom += w0;
        acc += w0 * h2[(size_t)s0 * NC + col];
    }
    out[(size_t)n * NC + col] = acc / denom + b2[col];
}

extern "C" void kernel_launch(void* const* d_in, const int* in_sizes, int n_in,
                              void* d_out, int out_size, void* d_ws, size_t ws_size,
                              hipStream_t stream) {
    const float* x   = (const float*)d_in[0];
    const int*   ei  = (const int*)d_in[1];
    const int*   esrc = ei;
    const int*   edst = ei + EE;
    const float* W1  = (const float*)d_in[2];
    const float* as1 = (const float*)d_in[3];
    const float* ad1 = (const float*)d_in[4];
    const float* b1  = (const float*)d_in[5];
    const float* W2  = (const float*)d_in[6];
    const float* as2 = (const float*)d_in[7];
    const float* ad2 = (const float*)d_in[8];
    const float* b2  = (const float*)d_in[9];
    float* out = (float*)d_out;

    char* w = (char*)d_ws;
    size_t off = 0;
    auto alloc = [&](size_t bytes) -> void* {
        void* p = w + off;
        off += (bytes + 255) & ~(size_t)255;
        return p;
    };
    unsigned short* h1b   = (unsigned short*)alloc((size_t)NN * C1 * 2);
    unsigned short* h2inb = (unsigned short*)alloc((size_t)NN * C1 * 2);
    int*   bucket = (int*)alloc((size_t)NN * BSTRIDE * 4);
    float* h2     = (float*)alloc((size_t)NN * NC * 4);
    float* a_src1 = (float*)alloc((size_t)NN * 4 * 4);
    float* a_dst1 = (float*)alloc((size_t)NN * 4 * 4);
    int*   cnt    = (int*)alloc((size_t)NN * 4);
    float* a_src2 = (float*)alloc((size_t)NN * 4);
    float* a_dst2 = (float*)alloc((size_t)NN * 4);
    __hip_bfloat16* W1t = (__hip_bfloat16*)alloc((size_t)C1 * INCH * 2);
    __hip_bfloat16* w2t = (__hip_bfloat16*)alloc((size_t)NC * C1 * 2);

    k_w1t<<<dim3(INCH / 32, C1 / 32), 256, 0, stream>>>(W1, W1t, W2, w2t, cnt);
    k_gemm1<<<TOTAL_BLKS, 256, 0, stream>>>(x, W1t, as1, ad1, h1b,
                                            a_src1, a_dst1, esrc, edst, cnt, bucket);
    k_agg1<<<(NN + 3) / 4, 256, 0, stream>>>(h1b, bucket, cnt, a_src1, a_dst1, b1, h2inb);
    k_gemm2<<<(NN + 63) / 64, 256, 0, stream>>>(h2inb, w2t, as2, ad2, h2, a_src2, a_dst2);
    k_agg2<<<(NN + 15) / 16, 256, 0, stream>>>(h2, bucket, cnt, a_src2, a_dst2, b2, out);
}

// Round 16
// 310.713 us; speedup vs baseline: 1.1028x; 1.1028x over previous
//
#include <hip/hip_runtime.h>
#include <hip/hip_bf16.h>
#include <math.h>

#define NN 50000
#define EE 800000
#define INCH 512
#define C1 256     // H1*HID
#define NC 16
#define NEG 0.2f
#define BSTRIDE 128   // bucket slots per node; Poisson(16) => P(deg>=128) ~ 1e-40

typedef __attribute__((ext_vector_type(8))) short bf16x8;
typedef __attribute__((ext_vector_type(4))) float f32x4;

__device__ inline short f2bf(float f) {
    __hip_bfloat16 h = __float2bfloat16(f);
    return *reinterpret_cast<short*>(&h);
}

__device__ inline void unpack4(uint2 rv, float& v0, float& v1, float& v2, float& v3) {
    v0 = __uint_as_float(rv.x << 16);
    v1 = __uint_as_float(rv.x & 0xFFFF0000u);
    v2 = __uint_as_float(rv.y << 16);
    v3 = __uint_as_float(rv.y & 0xFFFF0000u);
}

// -------- W1 transpose + bf16 (W2 transpose in block 0; cnt zeroing spread over grid) --------
__global__ __launch_bounds__(256) void k_w1t(const float* __restrict__ W1,
                                             __hip_bfloat16* __restrict__ W1t,
                                             const float* __restrict__ W2,
                                             __hip_bfloat16* __restrict__ w2t,
                                             int* __restrict__ cnt) {
    int blin = blockIdx.y * gridDim.x + blockIdx.x;   // 0..127
    for (int i = blin * 256 + threadIdx.x; i < NN; i += 128 * 256) cnt[i] = 0;
    if (blin == 0) {
        int t = threadIdx.x;
#pragma unroll
        for (int c = 0; c < NC; c++)
            w2t[(size_t)c * C1 + t] = __float2bfloat16(W2[(size_t)t * NC + c]);
    }
    __shared__ float t[32][33];
    int k0 = blockIdx.x * 32, n0 = blockIdx.y * 32;
    int tx = threadIdx.x & 31, ty = threadIdx.x >> 5;  // ty 0..7
#pragma unroll
    for (int i = 0; i < 4; i++) {
        t[ty + i * 8][tx] = W1[(size_t)(k0 + ty + i * 8) * C1 + n0 + tx];
    }
    __syncthreads();
#pragma unroll
    for (int i = 0; i < 4; i++) {
        W1t[(size_t)(n0 + ty + i * 8) * INCH + k0 + tx] = __float2bfloat16(t[tx][ty + i * 8]);
    }
}

// ---------------- GEMM1 (bf16 MFMA, 64x64 tile) + tail-fused one-pass bucket CSR build ----
// Gemm blocks first (XCD-aware: slot = l&7, head = (l>>3)&3, bm = (l>>5)*8+slot);
// edge blocks run in the gemm's drain phase (tail of grid).
#define BM3 64
#define BK3 64
#define NBM 782            // ceil(NN/64)
#define GEMM1_BLKS 3136    // 98 groups * 32
#define EDGE_BLKS 3125     // ceil(EE/256)
__global__ __launch_bounds__(256) void k_gemm1(const float* __restrict__ x,
                                               const __hip_bfloat16* __restrict__ W1t,
                                               const float* __restrict__ as1,
                                               const float* __restrict__ ad1,
                                               unsigned short* __restrict__ h1b,
                                               float* __restrict__ a_src,
                                               float* __restrict__ a_dst,
                                               const int* __restrict__ esrc,
                                               const int* __restrict__ edst,
                                               int* __restrict__ cnt,
                                               int* __restrict__ bucket) {
    int l = blockIdx.x;
    if (l >= GEMM1_BLKS) {
        // fused bucket CSR build: one atomic pass, no scan/place needed
        int e = (l - GEMM1_BLKS) * 256 + threadIdx.x;
        if (e < EE) {
            int d = edst[e];
            int s = esrc[e];
            int pos = atomicAdd(&cnt[d], 1);
            if (pos < BSTRIDE) bucket[(size_t)d * BSTRIDE + pos] = s;
        }
        return;
    }
    int g = l >> 5, r = l & 31;
    int head = r >> 3, slot = r & 7;
    int bmi = g * 8 + slot;
    if (bmi >= NBM) return;
    int bm = bmi * BM3;
    int bn = head * 64;

    __shared__ __align__(16) short Ah[BM3 * BK3];   // 8 KB
    __shared__ __align__(16) short Bl[BM3 * BK3];   // 8 KB
    int tid = threadIdx.x;
    int wm = tid >> 6, lane = tid & 63;
    int quad = lane >> 4, l16 = lane & 15;

    f32x4 acc[4];
#pragma unroll
    for (int j = 0; j < 4; j++) acc[j] = (f32x4){0.f, 0.f, 0.f, 0.f};

    for (int kt = 0; kt < INCH; kt += BK3) {
#pragma unroll
        for (int i = 0; i < 4; i++) {
            int idx = tid + 256 * i;
            int row = idx >> 4, c4 = idx & 15;
            int m = bm + row; if (m >= NN) m = NN - 1;
            float4 v = *(const float4*)&x[(size_t)m * INCH + kt + c4 * 4];
            short4 h4 = make_short4(f2bf(v.x), f2bf(v.y), f2bf(v.z), f2bf(v.w));
            int swc = (c4 >> 1) ^ (row & 7);
            *(short4*)&Ah[row * BK3 + swc * 8 + (c4 & 1) * 4] = h4;
        }
#pragma unroll
        for (int i = 0; i < 2; i++) {
            int idx = tid + 256 * i;
            int row = idx >> 3, c8 = idx & 7;
            float4 v = *(const float4*)(W1t + (size_t)(bn + row) * INCH + kt + c8 * 8);
            int swc = c8 ^ (row & 7);
            *(float4*)&Bl[row * BK3 + swc * 8] = v;
        }
        __syncthreads();
#pragma unroll
        for (int ks = 0; ks < 2; ks++) {
            int lc = (ks * 4 + quad);
            bf16x8 af, bfr[4];
            {
                int row = wm * 16 + l16;
                af = *(bf16x8*)&Ah[row * BK3 + (lc ^ (l16 & 7)) * 8];
            }
#pragma unroll
            for (int ni = 0; ni < 4; ni++) {
                int row = ni * 16 + l16;
                bfr[ni] = *(bf16x8*)&Bl[row * BK3 + (lc ^ (l16 & 7)) * 8];
            }
#pragma unroll
            for (int ni = 0; ni < 4; ni++)
                acc[ni] = __builtin_amdgcn_mfma_f32_16x16x32_bf16(af, bfr[ni], acc[ni], 0, 0, 0);
        }
        __syncthreads();
    }
    // store h1 as bf16 (C/D layout: col=l16, row=quad*4+r)
#pragma unroll
    for (int r2 = 0; r2 < 4; r2++) {
        int gm = bm + wm * 16 + quad * 4 + r2;
        if (gm < NN) {
#pragma unroll
            for (int ni = 0; ni < 4; ni++)
                h1b[(size_t)gm * C1 + bn + ni * 16 + l16] = (unsigned short)f2bf(acc[ni][r2]);
        }
    }
    // fused attention logits: wave covers the full head (64 cols)
    float aw[4], dw[4];
#pragma unroll
    for (int ni = 0; ni < 4; ni++) {
        aw[ni] = as1[bn + ni * 16 + l16];
        dw[ni] = ad1[bn + ni * 16 + l16];
    }
#pragma unroll
    for (int r2 = 0; r2 < 4; r2++) {
        float ps = acc[0][r2] * aw[0] + acc[1][r2] * aw[1] + acc[2][r2] * aw[2] + acc[3][r2] * aw[3];
        float pd = acc[0][r2] * dw[0] + acc[1][r2] * dw[1] + acc[2][r2] * dw[2] + acc[3][r2] * dw[3];
#pragma unroll
        for (int off = 8; off; off >>= 1) {
            ps += __shfl_xor(ps, off, 16);
            pd += __shfl_xor(pd, off, 16);
        }
        if (l16 == 0) {
            int gm = bm + wm * 16 + quad * 4 + r2;
            if (gm < NN) {
                a_src[gm * 4 + head] = ps;
                a_dst[gm * 4 + head] = pd;
            }
        }
    }
}

// ---------------- layer-1 aggregation: one wave per node, 4 ch/lane -> bf16 h2in ----------
__global__ __launch_bounds__(256) void k_agg1(const unsigned short* __restrict__ h1b,
                                              const int* __restrict__ bucket,
                                              const int* __restrict__ cnt,
                                              const float* __restrict__ a_src, const float* __restrict__ a_dst,
                                              const float* __restrict__ b1,
                                              unsigned short* __restrict__ h2inb) {
    int tid = threadIdx.x;
    int wv = tid >> 6, lane = tid & 63;
    int n = blockIdx.x * 4 + wv;
    if (n >= NN) return;
    int head = lane >> 4;
    const uint2* rows = (const uint2*)h1b;

    float adn = a_dst[n * 4 + head];
    float es = a_src[n * 4 + head] + adn;
    es = fmaxf(es, NEG * es);
    float wse = __expf(es);
    float denom = wse;
    float a0, a1, a2, a3;
    {
        uint2 rv = rows[(size_t)n * 64 + lane];
        float v0, v1, v2, v3;
        unpack4(rv, v0, v1, v2, v3);
        a0 = wse * v0; a1 = wse * v1; a2 = wse * v2; a3 = wse * v3;
    }

    size_t base = (size_t)n * BSTRIDE;
    int deg = cnt[n]; if (deg > BSTRIDE) deg = BSTRIDE;
    for (int c0 = 0; c0 < deg; c0 += 64) {
        int sv = 0;
        if (c0 + lane < deg) sv = bucket[base + c0 + lane];
        int m = deg - c0; if (m > 64) m = 64;
        int k = 0;
        for (; k + 4 <= m; k += 4) {
            int s0 = __shfl(sv, k + 0), s1 = __shfl(sv, k + 1);
            int s2 = __shfl(sv, k + 2), s3 = __shfl(sv, k + 3);
            float e0 = a_src[s0 * 4 + head] + adn;
            float e1 = a_src[s1 * 4 + head] + adn;
            float e2 = a_src[s2 * 4 + head] + adn;
            float e3 = a_src[s3 * 4 + head] + adn;
            uint2 r0 = rows[(size_t)s0 * 64 + lane];
            uint2 r1 = rows[(size_t)s1 * 64 + lane];
            uint2 r2 = rows[(size_t)s2 * 64 + lane];
            uint2 r3 = rows[(size_t)s3 * 64 + lane];
            e0 = fmaxf(e0, NEG * e0); e1 = fmaxf(e1, NEG * e1);
            e2 = fmaxf(e2, NEG * e2); e3 = fmaxf(e3, NEG * e3);
            float w0 = __expf(e0), w1 = __expf(e1), w2 = __expf(e2), w3 = __expf(e3);
            float v0, v1, v2, v3;
            unpack4(r0, v0, v1, v2, v3);
            denom += w0; a0 += w0 * v0; a1 += w0 * v1; a2 += w0 * v2; a3 += w0 * v3;
            unpack4(r1, v0, v1, v2, v3);
            denom += w1; a0 += w1 * v0; a1 += w1 * v1; a2 += w1 * v2; a3 += w1 * v3;
            unpack4(r2, v0, v1, v2, v3);
            denom += w2; a0 += w2 * v0; a1 += w2 * v1; a2 += w2 * v2; a3 += w2 * v3;
            unpack4(r3, v0, v1, v2, v3);
            denom += w3; a0 += w3 * v0; a1 += w3 * v1; a2 += w3 * v2; a3 += w3 * v3;
        }
        for (; k < m; k++) {
            int s0 = __shfl(sv, k);
            float e0 = a_src[s0 * 4 + head] + adn;
            uint2 r0 = rows[(size_t)s0 * 64 + lane];
            e0 = fmaxf(e0, NEG * e0);
            float w0 = __expf(e0);
            float v0, v1, v2, v3;
            unpack4(r0, v0, v1, v2, v3);
            denom += w0; a0 += w0 * v0; a1 += w0 * v1; a2 += w0 * v2; a3 += w0 * v3;
        }
    }
    float inv = 1.f / denom;
    float4 bv = *(const float4*)&b1[lane * 4];
    float o0 = a0 * inv + bv.x, o1 = a1 * inv + bv.y;
    float o2 = a2 * inv + bv.z, o3 = a3 * inv + bv.w;
    o0 = o0 > 0.f ? o0 : expm1f(o0);
    o1 = o1 > 0.f ? o1 : expm1f(o1);
    o2 = o2 > 0.f ? o2 : expm1f(o2);
    o3 = o3 > 0.f ? o3 : expm1f(o3);
    uint2 pk;
    pk.x = (unsigned int)(unsigned short)f2bf(o0) | ((unsigned int)(unsigned short)f2bf(o1) << 16);
    pk.y = (unsigned int)(unsigned short)f2bf(o2) | ((unsigned int)(unsigned short)f2bf(o3) << 16);
    *(uint2*)&h2inb[(size_t)n * C1 + lane * 4] = pk;
}

// ---------------- GEMM2 via MFMA: h2[NN,16] = h2in(bf16) @ W2, fused layer-2 logits -------
__global__ __launch_bounds__(256) void k_gemm2(const unsigned short* __restrict__ h2inb,
                                               const __hip_bfloat16* __restrict__ w2t,
                                               const float* __restrict__ as2, const float* __restrict__ ad2,
                                               float* __restrict__ h2,
                                               float* __restrict__ a_src2, float* __restrict__ a_dst2) {
    int tid = threadIdx.x;
    int wave = tid >> 6, lane = tid & 63;
    int quad = lane >> 4, l16 = lane & 15;
    int mbase = blockIdx.x * 64 + wave * 16;
    if (mbase >= NN) return;
    int mrow = mbase + l16; if (mrow >= NN) mrow = NN - 1;
    const bf16x8* arow = (const bf16x8*)(h2inb + (size_t)mrow * C1);
    f32x4 acc = (f32x4){0.f, 0.f, 0.f, 0.f};
#pragma unroll
    for (int ks = 0; ks < 8; ks++) {
        bf16x8 af = arow[ks * 4 + quad];
        bf16x8 bfv = *(const bf16x8*)(w2t + (size_t)l16 * C1 + ks * 32 + quad * 8);
        acc = __builtin_amdgcn_mfma_f32_16x16x32_bf16(af, bfv, acc, 0, 0, 0);
    }
    float a2 = as2[l16], d2 = ad2[l16];
#pragma unroll
    for (int r = 0; r < 4; r++) {
        int gm = mbase + quad * 4 + r;
        if (gm < NN) h2[(size_t)gm * NC + l16] = acc[r];
        float pa = acc[r] * a2, pb = acc[r] * d2;
#pragma unroll
        for (int off = 8; off; off >>= 1) {
            pa += __shfl_xor(pa, off, 16);
            pb += __shfl_xor(pb, off, 16);
        }
        if (l16 == 0 && gm < NN) {
            a_src2[gm] = pa;
            a_dst2[gm] = pb;
        }
    }
}

// ---------------- layer-2 aggregation: fused softmax + gather + bias -> out ----------------
__global__ __launch_bounds__(256) void k_agg2(const float* __restrict__ h2,
                                              const int* __restrict__ bucket,
                                              const int* __restrict__ cnt,
                                              const float* __restrict__ a_src2, const float* __restrict__ a_dst2,
                                              const float* __restrict__ b2, float* __restrict__ out) {
    int tid = threadIdx.x;
    int r = tid >> 4, col = tid & 15;
    int n = blockIdx.x * 16 + r;
    if (n >= NN) return;
    float adn = a_dst2[n];
    float es = a_src2[n] + adn;
    es = fmaxf(es, NEG * es);
    float wse = __expf(es);
    float denom = wse;
    float acc = wse * h2[(size_t)n * NC + col];
    size_t base = (size_t)n * BSTRIDE;
    int deg = cnt[n]; if (deg > BSTRIDE) deg = BSTRIDE;
    int k = 0;
    for (; k + 4 <= deg; k += 4) {
        int s0 = bucket[base + k + 0], s1 = bucket[base + k + 1];
        int s2 = bucket[base + k + 2], s3 = bucket[base + k + 3];
        float e0 = a_src2[s0] + adn, e1 = a_src2[s1] + adn;
        float e2 = a_src2[s2] + adn, e3 = a_src2[s3] + adn;
        float v0 = h2[(size_t)s0 * NC + col], v1 = h2[(size_t)s1 * NC + col];
        float v2 = h2[(size_t)s2 * NC + col], v3 = h2[(size_t)s3 * NC + col];
        e0 = fmaxf(e0, NEG * e0); e1 = fmaxf(e1, NEG * e1);
        e2 = fmaxf(e2, NEG * e2); e3 = fmaxf(e3, NEG * e3);
        float w0 = __expf(e0), w1 = __expf(e1), w2 = __expf(e2), w3 = __expf(e3);
        denom += w0; acc += w0 * v0;
        denom += w1; acc += w1 * v1;
        denom += w2; acc += w2 * v2;
        denom += w3; acc += w3 * v3;
    }
    for (; k < deg; k++) {
        int s0 = bucket[base + k];
        float e0 = a_src2[s0] + adn;
        e0 = fmaxf(e0, NEG * e0);
        float w0 = __expf(e0);
        denom += w0;
        acc += w0 * h2[(size_t)s0 * NC + col];
    }
    out[(size_t)n * NC + col] = acc / denom + b2[col];
}

extern "C" void kernel_launch(void* const* d_in, const int* in_sizes, int n_in,
                              void* d_out, int out_size, void* d_ws, size_t ws_size,
                              hipStream_t stream) {
    const float* x   = (const float*)d_in[0];
    const int*   ei  = (const int*)d_in[1];
    const int*   esrc = ei;
    const int*   edst = ei + EE;
    const float* W1  = (const float*)d_in[2];
    const float* as1 = (const float*)d_in[3];
    const float* ad1 = (const float*)d_in[4];
    const float* b1  = (const float*)d_in[5];
    const float* W2  = (const float*)d_in[6];
    const float* as2 = (const float*)d_in[7];
    const float* ad2 = (const float*)d_in[8];
    const float* b2  = (const float*)d_in[9];
    float* out = (float*)d_out;

    char* w = (char*)d_ws;
    size_t off = 0;
    auto alloc = [&](size_t bytes) -> void* {
        void* p = w + off;
        off += (bytes + 255) & ~(size_t)255;
        return p;
    };
    unsigned short* h1b   = (unsigned short*)alloc((size_t)NN * C1 * 2);
    unsigned short* h2inb = (unsigned short*)alloc((size_t)NN * C1 * 2);
    int*   bucket = (int*)alloc((size_t)NN * BSTRIDE * 4);
    float* h2     = (float*)alloc((size_t)NN * NC * 4);
    float* a_src1 = (float*)alloc((size_t)NN * 4 * 4);
    float* a_dst1 = (float*)alloc((size_t)NN * 4 * 4);
    int*   cnt    = (int*)alloc((size_t)NN * 4);
    float* a_src2 = (float*)alloc((size_t)NN * 4);
    float* a_dst2 = (float*)alloc((size_t)NN * 4);
    __hip_bfloat16* W1t = (__hip_bfloat16*)alloc((size_t)C1 * INCH * 2);
    __hip_bfloat16* w2t = (__hip_bfloat16*)alloc((size_t)NC * C1 * 2);

    k_w1t<<<dim3(INCH / 32, C1 / 32), 256, 0, stream>>>(W1, W1t, W2, w2t, cnt);
    k_gemm1<<<GEMM1_BLKS + EDGE_BLKS, 256, 0, stream>>>(x, W1t, as1, ad1, h1b,
                                                        a_src1, a_dst1, esrc, edst, cnt, bucket);
    k_agg1<<<(NN + 3) / 4, 256, 0, stream>>>(h1b, bucket, cnt, a_src1, a_dst1, b1, h2inb);
    k_gemm2<<<(NN + 63) / 64, 256, 0, stream>>>(h2inb, w2t, as2, ad2, h2, a_src2, a_dst2);
    k_agg2<<<(NN + 15) / 16, 256, 0, stream>>>(h2, bucket, cnt, a_src2, a_dst2, b2, out);
}